// Round 8
// baseline (48.756 us; speedup 1.0000x reference)
//
#include <hip/hip_runtime.h>
#include <math.h>

#define S 96
#define SM 95
#define TS 12
#define L2E 1.4426950408889634f

__device__ __forceinline__ float fexp2(float x) {
#if __has_builtin(__builtin_amdgcn_exp2f)
    return __builtin_amdgcn_exp2f(x);   // v_exp_f32: 2^x
#else
    return exp2f(x);
#endif
}
__device__ __forceinline__ float flog2(float x) {
#if __has_builtin(__builtin_amdgcn_logf)
    return __builtin_amdgcn_logf(x);    // v_log_f32: log2(x)
#else
    return log2f(x);
#endif
}

// constant-index float4 component select (folds at compile time)
__device__ __forceinline__ float f4c(const float4& v, int i) {
    return i == 0 ? v.x : i == 1 ? v.y : i == 2 ? v.z : v.w;
}

struct Tile {
    float4 d[3], s[3], c[9];
};

__device__ __forceinline__ void load_tile(Tile& T, const float4* dv,
                                          const float4* sv, const float4* cv,
                                          int tl) {
#pragma unroll
    for (int k = 0; k < 3; ++k) T.d[k] = dv[tl * 3 + k];
#pragma unroll
    for (int k = 0; k < 3; ++k) T.s[k] = sv[tl * 3 + k];
#pragma unroll
    for (int k = 0; k < 9; ++k) T.c[k] = cv[tl * 9 + k];
}

// atomic-fallback init (only if ws too small for slots)
__global__ void init_ws_kernel(unsigned int* ws) {
    ws[0] = 0x7F800000u;  // +inf
    ws[1] = 0xFF800000u;  // -inf
}

// ---------------------------------------------------------------------------
// Thread-per-ray serial marcher. Block = 1 wave = 64 rays.
// Per midpoint i (between samples i,i+1):
//   dd2 = (d_{i+1}-d_i) * log2(1+exp((s_i+s_{i+1})/2)); run += dd2;
//   T = exp2(-run); w_i = T_prev - T;  (1e-10 term negligible)
//   rgb += w*(c_i+c_{i+1})/2 etc. — all thread-local, no cross-lane.
// w staged in LDS [t*95+i] (bank-stride 31, conflict-free), block-coalesced
// float4 writeback of the contiguous [r0*95,(r0+64)*95) region.
// Depth stored raw (NaN->inf); tail_kernel clamps with global min/max.
// ---------------------------------------------------------------------------
template <bool SLOT>
__global__ __launch_bounds__(64) void march_kernel(
    const float* __restrict__ colors,
    const float* __restrict__ dens,
    const float* __restrict__ depths,
    const int* __restrict__ white_back,
    unsigned int* __restrict__ ws,
    float* __restrict__ out_rgb,   // [nrays,3]
    float* __restrict__ out_dep,   // [nrays] raw
    float* __restrict__ out_w,     // [nrays,95]
    int nrays, int nblocks) {
    __shared__ float wlds[64 * SM];   // 24320 B

    const int t = threadIdx.x;
    const int ray = blockIdx.x * 64 + t;
    const bool act = (ray < nrays);
    const int rayc = act ? ray : (nrays - 1);

    const float4* dv = (const float4*)(depths + (size_t)rayc * S);
    const float4* sv = (const float4*)(dens + (size_t)rayc * S);
    const float4* cv = (const float4*)(colors + (size_t)rayc * (3 * S));

    const float C1 = 0.5f * L2E;
    float run = 0.f, Tp = 1.f;
    float racc = 0.f, gacc = 0.f, bacc = 0.f, dacc = 0.f;

    Tile A, B;
    load_tile(A, dv, sv, cv, 0);
    // init prev = sample 0
    float d_p = A.d[0].x, s_p = A.s[0].x;
    float c0_p = A.c[0].x, c1_p = A.c[0].y, c2_p = A.c[0].z;
    const float dmin0 = d_p;

    // compute(T, base, SKIP0): midpoints i = base+k-1 for k=SKIP0..11
    auto compute = [&](const Tile& T, int base, bool skip0) {
#pragma unroll
        for (int k = 0; k < TS; ++k) {
            if (skip0 && k == 0) continue;
            float dc = f4c(T.d[k >> 2], k & 3);
            float sc = f4c(T.s[k >> 2], k & 3);
            float c0 = f4c(T.c[(3 * k) >> 2], (3 * k) & 3);
            float c1 = f4c(T.c[(3 * k + 1) >> 2], (3 * k + 1) & 3);
            float c2 = f4c(T.c[(3 * k + 2) >> 2], (3 * k + 2) & 3);
            float x2 = (s_p + sc) * C1;
            float sp = fmaxf(x2, 0.f) + flog2(1.f + fexp2(-fabsf(x2)));
            run += (dc - d_p) * sp;
            float Tc = fexp2(-run);
            float w = Tp - Tc;
            racc += w * (c0_p + c0);
            gacc += w * (c1_p + c1);
            bacc += w * (c2_p + c2);
            dacc += w * (d_p + dc);
            wlds[t * SM + (base + k - 1)] = w;
            d_p = dc; s_p = sc; c0_p = c0; c1_p = c1; c2_p = c2; Tp = Tc;
        }
    };

    // software-pipelined tiles: load t+1 while computing t
    load_tile(B, dv, sv, cv, 1);
    compute(A, 0, true);
    load_tile(A, dv, sv, cv, 2);
    compute(B, 12, false);
    load_tile(B, dv, sv, cv, 3);
    compute(A, 24, false);
    load_tile(A, dv, sv, cv, 4);
    compute(B, 36, false);
    load_tile(B, dv, sv, cv, 5);
    compute(A, 48, false);
    load_tile(A, dv, sv, cv, 6);
    compute(B, 60, false);
    load_tile(B, dv, sv, cv, 7);
    compute(A, 72, false);
    compute(B, 84, false);            // midpoints 83..94

    // ---- per-ray outputs (all thread-local)
    if (act) {
        float T95 = Tp;               // transmittance after sample 95
        float rr = 0.5f * racc, gg = 0.5f * gacc, bb = 0.5f * bacc;
        if (*white_back) { rr += T95; gg += T95; bb += T95; }  // 1-wtot = T95
        out_rgb[(size_t)ray * 3 + 0] = rr;
        out_rgb[(size_t)ray * 3 + 1] = gg;
        out_rgb[(size_t)ray * 3 + 2] = bb;
        float cd = 0.5f * dacc;
        if (isnan(cd)) cd = INFINITY;  // nan_to_num(nan=inf)
        out_dep[ray] = cd;             // clamped by tail_kernel
    }

    // ---- wave min/max of depth bounds (depths sorted per ray)
    float mn = act ? dmin0 : INFINITY;
    float mx = act ? d_p : -INFINITY;  // d_p == d[95]
#pragma unroll
    for (int off = 32; off >= 1; off >>= 1) {
        mn = fminf(mn, __shfl_xor(mn, off));
        mx = fmaxf(mx, __shfl_xor(mx, off));
    }
    if (t == 0) {
        if (SLOT) {
            float* sl = (float*)ws;
            sl[2 + blockIdx.x] = mn;
            sl[2 + nblocks + blockIdx.x] = mx;
        } else {
            atomicMin((int*)&ws[0], __float_as_int(mn));
            atomicMax((int*)&ws[1], __float_as_int(mx));
        }
    }

    // ---- coalesced w writeback: block region is contiguous in global
    __syncthreads();
    const int totalF = (min(64, nrays - blockIdx.x * 64)) * SM;
    float* wdst = out_w + (size_t)blockIdx.x * 64 * SM;
    const float4* wsrc4 = (const float4*)wlds;
    float4* wdst4 = (float4*)wdst;
    for (int i4 = t; i4 * 4 + 3 < totalF; i4 += 64) wdst4[i4] = wsrc4[i4];
    for (int i = (totalF & ~3) + t; i < totalF; i += 64) wdst[i] = wlds[i];
}

// Merged finalize+clamp (R6, proven): every block redundantly reduces the
// slot array then clamps its contiguous chunk of out_dep.
__global__ __launch_bounds__(256) void tail_kernel(
    float* __restrict__ dep, const unsigned int* __restrict__ ws,
    int n, int nblocks, int slotMode) {
    float gmn, gmx;
    if (slotMode) {
        const float* sl = (const float*)ws + 2;
        float mn = INFINITY, mx = -INFINITY;
        for (int i = threadIdx.x; i < nblocks; i += 256) {
            mn = fminf(mn, sl[i]);
            mx = fmaxf(mx, sl[i + nblocks]);
        }
#pragma unroll
        for (int off = 32; off >= 1; off >>= 1) {
            mn = fminf(mn, __shfl_xor(mn, off));
            mx = fmaxf(mx, __shfl_xor(mx, off));
        }
        __shared__ float a[4], b[4];
        const int wv = threadIdx.x >> 6;
        if ((threadIdx.x & 63) == 0) { a[wv] = mn; b[wv] = mx; }
        __syncthreads();
        gmn = fminf(fminf(a[0], a[1]), fminf(a[2], a[3]));
        gmx = fmaxf(fmaxf(b[0], b[1]), fmaxf(b[2], b[3]));
    } else {
        gmn = __int_as_float((int)ws[0]);
        gmx = __int_as_float((int)ws[1]);
    }
    int i = blockIdx.x * 256 + threadIdx.x;
    if (i < n) dep[i] = fminf(fmaxf(dep[i], gmn), gmx);
}

extern "C" void kernel_launch(void* const* d_in, const int* in_sizes, int n_in,
                              void* d_out, int out_size, void* d_ws, size_t ws_size,
                              hipStream_t stream) {
    const float* colors = (const float*)d_in[0];
    const float* dens = (const float*)d_in[1];
    const float* depths = (const float*)d_in[2];
    const int* white_back = (const int*)d_in[3];

    const int nrays = in_sizes[1] / S;  // densities: nrays * S
    unsigned int* ws = (unsigned int*)d_ws;

    float* out_rgb = (float*)d_out;                // nrays*3
    float* out_dep = out_rgb + (size_t)nrays * 3;  // nrays
    float* out_w = out_dep + nrays;                // nrays*95

    const int nblocks = (nrays + 63) / 64;         // 1 wave (64 rays) / block
    const bool slot = ws_size >= (size_t)(2 + 2 * nblocks) * sizeof(float);

    if (slot) {
        march_kernel<true><<<nblocks, 64, 0, stream>>>(
            colors, dens, depths, white_back, ws, out_rgb, out_dep, out_w,
            nrays, nblocks);
    } else {
        init_ws_kernel<<<1, 1, 0, stream>>>(ws);
        march_kernel<false><<<nblocks, 64, 0, stream>>>(
            colors, dens, depths, white_back, ws, out_rgb, out_dep, out_w,
            nrays, nblocks);
    }
    tail_kernel<<<(nrays + 255) / 256, 256, 0, stream>>>(
        out_dep, ws, nrays, nblocks, slot ? 1 : 0);
}

// Round 9
// 47.367 us; speedup vs baseline: 1.0293x; 1.0293x over previous
//
#include <hip/hip_runtime.h>
#include <math.h>

#define S 96
#define SM 95
#define L2E 1.4426950408889634f

__device__ __forceinline__ float fexp2(float x) {
#if __has_builtin(__builtin_amdgcn_exp2f)
    return __builtin_amdgcn_exp2f(x);   // v_exp_f32: 2^x
#else
    return exp2f(x);
#endif
}
__device__ __forceinline__ float flog2(float x) {
#if __has_builtin(__builtin_amdgcn_logf)
    return __builtin_amdgcn_logf(x);    // v_log_f32: log2(x)
#else
    return log2f(x);
#endif
}

// DPP helper: dest = lane selected by CTRL (invalid lanes -> 0).
template <int CTRL, int RMASK>
__device__ __forceinline__ float updpp0(float src) {
    return __int_as_float(__builtin_amdgcn_update_dpp(
        0, __float_as_int(src), CTRL, RMASK, 0xF, false));
}

// 64-lane inclusive prefix-sum (all VALU, canonical gfx9 DPP ladder).
__device__ __forceinline__ float dpp_scan_add(float x) {
    x += updpp0<0x111, 0xF>(x);  // row_shr:1
    x += updpp0<0x112, 0xF>(x);  // row_shr:2
    x += updpp0<0x114, 0xF>(x);  // row_shr:4
    x += updpp0<0x118, 0xF>(x);  // row_shr:8
    x += updpp0<0x142, 0xA>(x);  // row_bcast:15 -> rows 1,3
    x += updpp0<0x143, 0xC>(x);  // row_bcast:31 -> rows 2,3
    return x;                    // lane 63 = wave total
}

__device__ __forceinline__ float rdlane(float x, int lane) {
    return __int_as_float(__builtin_amdgcn_readlane(__float_as_int(x), lane));
}
__device__ __forceinline__ float wave_sum(float x) {
    return rdlane(dpp_scan_add(x), 63);
}
// wave-wide lane shifts (VALU): shr1 = shfl_up(1), shl1 = shfl_down(1)
__device__ __forceinline__ float wshr1(float x) { return updpp0<0x138, 0xF>(x); }
__device__ __forceinline__ float wshl1(float x) { return updpp0<0x130, 0xF>(x); }

// atomic-fallback init (only if ws too small for slots)
__global__ void init_ws_kernel(unsigned int* ws) {
    ws[0] = 0x7F800000u;  // +inf
    ws[1] = 0xFF800000u;  // -inf
}

// ---------------------------------------------------------------------------
// One wave per ray (4 rays / 256-thread block) — the R5 structure verbatim.
// Samples j=0..95: batch a = lane l (j=l); batch b = lane l (j=64+l, l<32).
// Log-space: dd2_i = (d_{i+1}-d_i)*log2(1+exp(x_i)); T_j = exp2(-prefix).
// w_i = T_i - T_{i+1}; v_j = 0.5*(T_{j-1}-T_{j+1}); 1-wtot = T_95.
// Per-block depth bounds -> slot array (or atomics fallback).
// Depth stored raw (NaN->inf); tail_kernel clamps.
// ---------------------------------------------------------------------------
template <bool SLOT>
__global__ __launch_bounds__(256) void march_kernel(
    const float* __restrict__ colors,
    const float* __restrict__ dens,
    const float* __restrict__ depths,
    const int* __restrict__ white_back,
    unsigned int* __restrict__ ws,
    float* __restrict__ out_rgb,   // [nrays,3]
    float* __restrict__ out_dep,   // [nrays] raw
    float* __restrict__ out_w,     // [nrays,95]
    int nrays, int nblocks) {
    __shared__ float smn[4], smx[4];
    const int wv = threadIdx.x >> 6;
    const int l = threadIdx.x & 63;
    const int ray0 = blockIdx.x * 4 + wv;
    const bool valid = (ray0 < nrays);
    const int ray = valid ? ray0 : (nrays - 1);
    const int wb = *white_back;

    const float* db = depths + (size_t)ray * S;
    const float* sb = dens + (size_t)ray * S;
    const float3* cb3 = (const float3*)(colors + (size_t)ray * (3 * S));

    // batch-a loads (sample j = l): dword + dword + dwordx3, lane-coalesced
    float d_a = db[l];
    float s_a = sb[l];
    float3 ca = cb3[l];
    // batch-b loads (sample j = 64+l), lanes 0..31
    const bool hb = (l < 32);
    float d_b = 0.f, s_b = 0.f;
    float3 cbv = {0.f, 0.f, 0.f};
    if (hb) {
        d_b = db[64 + l];
        s_b = sb[64 + l];
        cbv = cb3[64 + l];
    }

    // ---- per-ray depth bounds (sorted): d[0]=lane0 d_a, d[95]=lane31 d_b
    float rmn = rdlane(d_a, 0);
    float rmx = rdlane(d_b, 31);
    if (!valid) { rmn = INFINITY; rmx = -INFINITY; }
    if (l == 0) { smn[wv] = rmn; smx[wv] = rmx; }
    __syncthreads();
    if (threadIdx.x == 0) {
        float bmn = fminf(fminf(smn[0], smn[1]), fminf(smn[2], smn[3]));
        float bmx = fmaxf(fmaxf(smx[0], smx[1]), fmaxf(smx[2], smx[3]));
        if (SLOT) {
            float* sl = (float*)ws;
            sl[2 + blockIdx.x] = bmn;
            sl[2 + nblocks + blockIdx.x] = bmx;
        } else {
            atomicMin((int*)&ws[0], __float_as_int(bmn));
            atomicMax((int*)&ws[1], __float_as_int(bmx));
        }
    }

    // ---- neighbors via wave shifts (VALU)
    float dn_a = wshl1(d_a);
    float sn_a = wshl1(s_a);
    {
        float d64 = rdlane(d_b, 0);
        float s64 = rdlane(s_b, 0);
        if (l == 63) { dn_a = d64; sn_a = s64; }
    }
    float dn_b = wshl1(d_b);
    float sn_b = wshl1(s_b);

    // ---- log2-space density*delta per midpoint
    const float C1 = 0.5f * L2E;
    float x_a = (s_a + sn_a) * C1;
    float lg_a = fmaxf(x_a, 0.f) + flog2(1.f + fexp2(-fabsf(x_a)));
    float dd_a = (dn_a - d_a) * lg_a;                    // midpoint l
    float x_b = (s_b + sn_b) * C1;
    float lg_b = fmaxf(x_b, 0.f) + flog2(1.f + fexp2(-fabsf(x_b)));
    float dd_b = (l <= 30) ? (dn_b - d_b) * lg_b : 0.f;  // midpoint 64+l

    // ---- DPP scans (VALU pipe)
    float A = dpp_scan_add(dd_a);
    float P = rdlane(A, 63);
    float Bc = dpp_scan_add(dd_b);

    float Ti_a = fexp2(-A);              // T_{l+1}
    float Ti_b = fexp2(-(P + Bc));       // T_{65+l} (l=31 -> T_96:=T_95)
    float T63 = rdlane(Ti_a, 62);
    float T64 = rdlane(Ti_a, 63);
    float T95 = rdlane(Ti_b, 31);

    float Te_a = wshr1(Ti_a);            // T_l
    if (l == 0) Te_a = 1.f;
    float Te_b = wshr1(Ti_b);            // T_{64+l}
    if (l == 0) Te_b = T64;
    float Tm1_a = wshr1(Te_a);           // T_{l-1} (lane1 <- Te_a[0]=1 ok)
    if (l == 0) Tm1_a = 1.f;             // T_{-1} := 1
    float Tm1_b = wshr1(Te_b);           // T_{63+l} (lane1 <- T64 ok)
    if (l == 0) Tm1_b = T63;

    float w_a = Te_a - Ti_a;             // weight midpoint l
    float w_b = Te_b - Ti_b;             // weight midpoint 64+l (l<=30)
    float v_a = 0.5f * (Tm1_a - Ti_a);             // coeff sample l
    float v_b = hb ? 0.5f * (Tm1_b - Ti_b) : 0.f;  // coeff sample 64+l

    // ---- weighted sums over samples (DPP reductions)
    float r_sum = wave_sum(v_a * ca.x + v_b * cbv.x);
    float g_sum = wave_sum(v_a * ca.y + v_b * cbv.y);
    float b_sum = wave_sum(v_a * ca.z + v_b * cbv.z);
    float dep_sum = wave_sum(v_a * d_a + v_b * d_b);

    if (!valid) return;   // after syncthreads; per-ray outputs only below

    float* wout = out_w + (size_t)ray * SM;
    wout[l] = w_a;                    // midpoints 0..63
    if (l <= 30) wout[64 + l] = w_b;  // midpoints 64..94

    if (l == 0) {
        float rr = r_sum, gg = g_sum, bb = b_sum;
        if (wb) { rr += T95; gg += T95; bb += T95; }  // 1-wtot = T_95
        out_rgb[(size_t)ray * 3 + 0] = rr;
        out_rgb[(size_t)ray * 3 + 1] = gg;
        out_rgb[(size_t)ray * 3 + 2] = bb;
        float cd = dep_sum;
        if (isnan(cd)) cd = INFINITY;   // nan_to_num(nan=inf)
        out_dep[ray] = cd;              // clamped by tail_kernel
    }
}

// Merged finalize+clamp (R6, proven): every block redundantly reduces the
// slot array (L2-resident) then clamps its contiguous chunk of out_dep.
__global__ __launch_bounds__(256) void tail_kernel(
    float* __restrict__ dep, const unsigned int* __restrict__ ws,
    int n, int nblocks, int slotMode) {
    float gmn, gmx;
    if (slotMode) {
        const float* sl = (const float*)ws + 2;
        float mn = INFINITY, mx = -INFINITY;
        for (int i = threadIdx.x; i < nblocks; i += 256) {
            mn = fminf(mn, sl[i]);
            mx = fmaxf(mx, sl[i + nblocks]);
        }
#pragma unroll
        for (int off = 32; off >= 1; off >>= 1) {
            mn = fminf(mn, __shfl_xor(mn, off));
            mx = fmaxf(mx, __shfl_xor(mx, off));
        }
        __shared__ float a[4], b[4];
        const int wv = threadIdx.x >> 6;
        if ((threadIdx.x & 63) == 0) { a[wv] = mn; b[wv] = mx; }
        __syncthreads();
        gmn = fminf(fminf(a[0], a[1]), fminf(a[2], a[3]));
        gmx = fmaxf(fmaxf(b[0], b[1]), fmaxf(b[2], b[3]));
    } else {
        gmn = __int_as_float((int)ws[0]);
        gmx = __int_as_float((int)ws[1]);
    }
    int i = blockIdx.x * 256 + threadIdx.x;
    if (i < n) dep[i] = fminf(fmaxf(dep[i], gmn), gmx);
}

extern "C" void kernel_launch(void* const* d_in, const int* in_sizes, int n_in,
                              void* d_out, int out_size, void* d_ws, size_t ws_size,
                              hipStream_t stream) {
    const float* colors = (const float*)d_in[0];
    const float* dens = (const float*)d_in[1];
    const float* depths = (const float*)d_in[2];
    const int* white_back = (const int*)d_in[3];

    const int nrays = in_sizes[1] / S;  // densities: nrays * S
    unsigned int* ws = (unsigned int*)d_ws;

    float* out_rgb = (float*)d_out;                // nrays*3
    float* out_dep = out_rgb + (size_t)nrays * 3;  // nrays
    float* out_w = out_dep + nrays;                // nrays*95

    const int nblocks = (nrays + 3) / 4;           // 4 rays (waves) per block
    const bool slot = ws_size >= (size_t)(2 + 2 * nblocks) * sizeof(float);

    if (slot) {
        march_kernel<true><<<nblocks, 256, 0, stream>>>(
            colors, dens, depths, white_back, ws, out_rgb, out_dep, out_w,
            nrays, nblocks);
    } else {
        init_ws_kernel<<<1, 1, 0, stream>>>(ws);
        march_kernel<false><<<nblocks, 256, 0, stream>>>(
            colors, dens, depths, white_back, ws, out_rgb, out_dep, out_w,
            nrays, nblocks);
    }
    tail_kernel<<<(nrays + 255) / 256, 256, 0, stream>>>(
        out_dep, ws, nrays, nblocks, slot ? 1 : 0);
}

// Round 10
// 33.326 us; speedup vs baseline: 1.4630x; 1.4213x over previous
//
#include <hip/hip_runtime.h>
#include <math.h>

#define S 96
#define SM 95
#define WPB 16           // waves (rays) per march block
#define L2E 1.4426950408889634f

__device__ __forceinline__ float fexp2(float x) {
#if __has_builtin(__builtin_amdgcn_exp2f)
    return __builtin_amdgcn_exp2f(x);   // v_exp_f32: 2^x
#else
    return exp2f(x);
#endif
}
__device__ __forceinline__ float flog2(float x) {
#if __has_builtin(__builtin_amdgcn_logf)
    return __builtin_amdgcn_logf(x);    // v_log_f32: log2(x)
#else
    return log2f(x);
#endif
}

// DPP helper: dest = lane selected by CTRL (invalid lanes -> 0).
template <int CTRL, int RMASK>
__device__ __forceinline__ float updpp0(float src) {
    return __int_as_float(__builtin_amdgcn_update_dpp(
        0, __float_as_int(src), CTRL, RMASK, 0xF, false));
}

// 64-lane inclusive prefix-sum (all VALU, canonical gfx9 DPP ladder).
__device__ __forceinline__ float dpp_scan_add(float x) {
    x += updpp0<0x111, 0xF>(x);  // row_shr:1
    x += updpp0<0x112, 0xF>(x);  // row_shr:2
    x += updpp0<0x114, 0xF>(x);  // row_shr:4
    x += updpp0<0x118, 0xF>(x);  // row_shr:8
    x += updpp0<0x142, 0xA>(x);  // row_bcast:15 -> rows 1,3
    x += updpp0<0x143, 0xC>(x);  // row_bcast:31 -> rows 2,3
    return x;                    // lane 63 = wave total
}

__device__ __forceinline__ float rdlane(float x, int lane) {
    return __int_as_float(__builtin_amdgcn_readlane(__float_as_int(x), lane));
}
__device__ __forceinline__ float wave_sum(float x) {
    return rdlane(dpp_scan_add(x), 63);
}
// wave-wide lane shifts (VALU): shr1 = shfl_up(1), shl1 = shfl_down(1)
__device__ __forceinline__ float wshr1(float x) { return updpp0<0x138, 0xF>(x); }
__device__ __forceinline__ float wshl1(float x) { return updpp0<0x130, 0xF>(x); }

// atomic-fallback init (only if ws too small for slots)
__global__ void init_ws_kernel(unsigned int* ws) {
    ws[0] = 0x7F800000u;  // +inf
    ws[1] = 0xFF800000u;  // -inf
}

// ---------------------------------------------------------------------------
// One wave per ray, 16 rays per 1024-thread block (R5 wave code verbatim).
// Samples j=0..95: batch a = lane l (j=l); batch b = lane l (j=64+l, l<32).
// Log-space: dd2_i = (d_{i+1}-d_i)*log2(1+exp(x_i)); T_j = exp2(-prefix).
// w_i = T_i - T_{i+1}; v_j = 0.5*(T_{j-1}-T_{j+1}); 1-wtot = T_95.
// Slot mode: block min/max -> ws[blk] / ws[nblocks+blk] (16B-aligned arrays).
// Depth stored raw (NaN->inf); tail_kernel clamps.
// ---------------------------------------------------------------------------
template <bool SLOT>
__global__ __launch_bounds__(WPB * 64) void march_kernel(
    const float* __restrict__ colors,
    const float* __restrict__ dens,
    const float* __restrict__ depths,
    const int* __restrict__ white_back,
    unsigned int* __restrict__ ws,
    float* __restrict__ out_rgb,   // [nrays,3]
    float* __restrict__ out_dep,   // [nrays] raw
    float* __restrict__ out_w,     // [nrays,95]
    int nrays, int nblocks) {
    __shared__ float smn[WPB], smx[WPB];
    const int wv = threadIdx.x >> 6;
    const int l = threadIdx.x & 63;
    const int ray0 = blockIdx.x * WPB + wv;
    const bool valid = (ray0 < nrays);
    const int ray = valid ? ray0 : (nrays - 1);
    const int wb = *white_back;

    const float* db = depths + (size_t)ray * S;
    const float* sb = dens + (size_t)ray * S;
    const float3* cb3 = (const float3*)(colors + (size_t)ray * (3 * S));

    // batch-a loads (sample j = l)
    float d_a = db[l];
    float s_a = sb[l];
    float3 ca = cb3[l];
    // batch-b loads (sample j = 64+l), lanes 0..31
    const bool hb = (l < 32);
    float d_b = 0.f, s_b = 0.f;
    float3 cbv = {0.f, 0.f, 0.f};
    if (hb) {
        d_b = db[64 + l];
        s_b = sb[64 + l];
        cbv = cb3[64 + l];
    }

    // ---- per-ray depth bounds (sorted): d[0]=lane0 d_a, d[95]=lane31 d_b
    float rmn = rdlane(d_a, 0);
    float rmx = rdlane(d_b, 31);
    if (!valid) { rmn = INFINITY; rmx = -INFINITY; }
    if (l == 0) { smn[wv] = rmn; smx[wv] = rmx; }
    __syncthreads();
    if (threadIdx.x == 0) {
        float bmn = smn[0], bmx = smx[0];
#pragma unroll
        for (int i = 1; i < WPB; ++i) {
            bmn = fminf(bmn, smn[i]);
            bmx = fmaxf(bmx, smx[i]);
        }
        if (SLOT) {
            float* sl = (float*)ws;
            sl[blockIdx.x] = bmn;
            sl[nblocks + blockIdx.x] = bmx;
        } else {
            atomicMin((int*)&ws[0], __float_as_int(bmn));
            atomicMax((int*)&ws[1], __float_as_int(bmx));
        }
    }

    // ---- neighbors via wave shifts (VALU)
    float dn_a = wshl1(d_a);
    float sn_a = wshl1(s_a);
    {
        float d64 = rdlane(d_b, 0);
        float s64 = rdlane(s_b, 0);
        if (l == 63) { dn_a = d64; sn_a = s64; }
    }
    float dn_b = wshl1(d_b);
    float sn_b = wshl1(s_b);

    // ---- log2-space density*delta per midpoint
    const float C1 = 0.5f * L2E;
    float x_a = (s_a + sn_a) * C1;
    float lg_a = fmaxf(x_a, 0.f) + flog2(1.f + fexp2(-fabsf(x_a)));
    float dd_a = (dn_a - d_a) * lg_a;                    // midpoint l
    float x_b = (s_b + sn_b) * C1;
    float lg_b = fmaxf(x_b, 0.f) + flog2(1.f + fexp2(-fabsf(x_b)));
    float dd_b = (l <= 30) ? (dn_b - d_b) * lg_b : 0.f;  // midpoint 64+l

    // ---- DPP scans (VALU pipe)
    float A = dpp_scan_add(dd_a);
    float P = rdlane(A, 63);
    float Bc = dpp_scan_add(dd_b);

    float Ti_a = fexp2(-A);              // T_{l+1}
    float Ti_b = fexp2(-(P + Bc));       // T_{65+l} (l=31 -> T_96:=T_95)
    float T63 = rdlane(Ti_a, 62);
    float T64 = rdlane(Ti_a, 63);
    float T95 = rdlane(Ti_b, 31);

    float Te_a = wshr1(Ti_a);            // T_l
    if (l == 0) Te_a = 1.f;
    float Te_b = wshr1(Ti_b);            // T_{64+l}
    if (l == 0) Te_b = T64;
    float Tm1_a = wshr1(Te_a);           // T_{l-1} (lane1 <- Te_a[0]=1 ok)
    if (l == 0) Tm1_a = 1.f;             // T_{-1} := 1
    float Tm1_b = wshr1(Te_b);           // T_{63+l} (lane1 <- T64 ok)
    if (l == 0) Tm1_b = T63;

    float w_a = Te_a - Ti_a;             // weight midpoint l
    float w_b = Te_b - Ti_b;             // weight midpoint 64+l (l<=30)
    float v_a = 0.5f * (Tm1_a - Ti_a);             // coeff sample l
    float v_b = hb ? 0.5f * (Tm1_b - Ti_b) : 0.f;  // coeff sample 64+l

    // ---- weighted sums over samples (DPP reductions)
    float r_sum = wave_sum(v_a * ca.x + v_b * cbv.x);
    float g_sum = wave_sum(v_a * ca.y + v_b * cbv.y);
    float b_sum = wave_sum(v_a * ca.z + v_b * cbv.z);
    float dep_sum = wave_sum(v_a * d_a + v_b * d_b);

    if (!valid) return;   // after syncthreads; per-ray outputs only below

    float* wout = out_w + (size_t)ray * SM;
    wout[l] = w_a;                    // midpoints 0..63
    if (l <= 30) wout[64 + l] = w_b;  // midpoints 64..94

    if (l == 0) {
        float rr = r_sum, gg = g_sum, bb = b_sum;
        if (wb) { rr += T95; gg += T95; bb += T95; }  // 1-wtot = T_95
        out_rgb[(size_t)ray * 3 + 0] = rr;
        out_rgb[(size_t)ray * 3 + 1] = gg;
        out_rgb[(size_t)ray * 3 + 2] = bb;
        float cd = dep_sum;
        if (isnan(cd)) cd = INFINITY;   // nan_to_num(nan=inf)
        out_dep[ray] = cd;              // clamped by tail_kernel
    }
}

// Merged finalize+clamp: every block redundantly reduces the slot arrays
// (float4, L2-resident, 4 iter/thread at nblocks=4096) then clamps its
// contiguous chunk of out_dep.
__global__ __launch_bounds__(256) void tail_kernel(
    float* __restrict__ dep, const unsigned int* __restrict__ ws,
    int n, int nblocks, int slotMode) {
    float gmn, gmx;
    if (slotMode) {
        const float* sl = (const float*)ws;
        float mn = INFINITY, mx = -INFINITY;
        const int nv = nblocks >> 2;                    // float4 count
        const float4* mn4 = (const float4*)sl;
        const float4* mx4 = (const float4*)(sl + nblocks);
        for (int i = threadIdx.x; i < nv; i += 256) {
            float4 a = mn4[i];
            float4 b = mx4[i];
            mn = fminf(mn, fminf(fminf(a.x, a.y), fminf(a.z, a.w)));
            mx = fmaxf(mx, fmaxf(fmaxf(b.x, b.y), fmaxf(b.z, b.w)));
        }
        for (int i = (nv << 2) + threadIdx.x; i < nblocks; i += 256) {
            mn = fminf(mn, sl[i]);
            mx = fmaxf(mx, sl[nblocks + i]);
        }
#pragma unroll
        for (int off = 32; off >= 1; off >>= 1) {
            mn = fminf(mn, __shfl_xor(mn, off));
            mx = fmaxf(mx, __shfl_xor(mx, off));
        }
        __shared__ float a[4], b[4];
        const int wv = threadIdx.x >> 6;
        if ((threadIdx.x & 63) == 0) { a[wv] = mn; b[wv] = mx; }
        __syncthreads();
        gmn = fminf(fminf(a[0], a[1]), fminf(a[2], a[3]));
        gmx = fmaxf(fmaxf(b[0], b[1]), fmaxf(b[2], b[3]));
    } else {
        gmn = __int_as_float((int)ws[0]);
        gmx = __int_as_float((int)ws[1]);
    }
    int i = blockIdx.x * 256 + threadIdx.x;
    if (i < n) dep[i] = fminf(fmaxf(dep[i], gmn), gmx);
}

extern "C" void kernel_launch(void* const* d_in, const int* in_sizes, int n_in,
                              void* d_out, int out_size, void* d_ws, size_t ws_size,
                              hipStream_t stream) {
    const float* colors = (const float*)d_in[0];
    const float* dens = (const float*)d_in[1];
    const float* depths = (const float*)d_in[2];
    const int* white_back = (const int*)d_in[3];

    const int nrays = in_sizes[1] / S;  // densities: nrays * S
    unsigned int* ws = (unsigned int*)d_ws;

    float* out_rgb = (float*)d_out;                // nrays*3
    float* out_dep = out_rgb + (size_t)nrays * 3;  // nrays
    float* out_w = out_dep + nrays;                // nrays*95

    const int nblocks = (nrays + WPB - 1) / WPB;   // 16 rays (waves) / block
    const bool slot = ws_size >= (size_t)(2 * nblocks) * sizeof(float);

    if (slot) {
        march_kernel<true><<<nblocks, WPB * 64, 0, stream>>>(
            colors, dens, depths, white_back, ws, out_rgb, out_dep, out_w,
            nrays, nblocks);
    } else {
        init_ws_kernel<<<1, 1, 0, stream>>>(ws);
        march_kernel<false><<<nblocks, WPB * 64, 0, stream>>>(
            colors, dens, depths, white_back, ws, out_rgb, out_dep, out_w,
            nrays, nblocks);
    }
    tail_kernel<<<(nrays + 255) / 256, 256, 0, stream>>>(
        out_dep, ws, nrays, nblocks, slot ? 1 : 0);
}

// Round 11
// 32.277 us; speedup vs baseline: 1.5105x; 1.0325x over previous
//
#include <hip/hip_runtime.h>
#include <math.h>

#define S 96
#define SM 95
#define WPB 16           // waves per march block; 2 rays/wave -> 32 rays/block
#define L2E 1.4426950408889634f

__device__ __forceinline__ float fexp2(float x) {
#if __has_builtin(__builtin_amdgcn_exp2f)
    return __builtin_amdgcn_exp2f(x);   // v_exp_f32: 2^x
#else
    return exp2f(x);
#endif
}
__device__ __forceinline__ float flog2(float x) {
#if __has_builtin(__builtin_amdgcn_logf)
    return __builtin_amdgcn_logf(x);    // v_log_f32: log2(x)
#else
    return log2f(x);
#endif
}

// DPP helper: dest = lane selected by CTRL (invalid lanes -> 0).
template <int CTRL, int RMASK>
__device__ __forceinline__ float updpp0(float src) {
    return __int_as_float(__builtin_amdgcn_update_dpp(
        0, __float_as_int(src), CTRL, RMASK, 0xF, false));
}

// 32-lane inclusive prefix-sum within each wave half (5 DPP, all VALU).
// After: lane 31 holds sum of lanes 0..31, lane 63 holds sum of 32..63.
__device__ __forceinline__ float scan32(float x) {
    x += updpp0<0x111, 0xF>(x);  // row_shr:1
    x += updpp0<0x112, 0xF>(x);  // row_shr:2
    x += updpp0<0x114, 0xF>(x);  // row_shr:4
    x += updpp0<0x118, 0xF>(x);  // row_shr:8
    x += updpp0<0x142, 0xA>(x);  // row_bcast:15 -> rows 1,3 (stays in half)
    return x;
}

__device__ __forceinline__ float rdlane(float x, int lane) {
    return __int_as_float(__builtin_amdgcn_readlane(__float_as_int(x), lane));
}
// wave-wide lane shifts (VALU): shr1: lane l <- l-1; shl1: lane l <- l+1
__device__ __forceinline__ float wshr1(float x) { return updpp0<0x138, 0xF>(x); }
__device__ __forceinline__ float wshl1(float x) { return updpp0<0x130, 0xF>(x); }

// atomic-fallback init (only if ws too small for slots)
__global__ void init_ws_kernel(unsigned int* ws) {
    ws[0] = 0x7F800000u;  // +inf
    ws[1] = 0xFF800000u;  // -inf
}

// ---------------------------------------------------------------------------
// TWO rays per wave: lanes 0-31 = ray 2w, lanes 32-63 = ray 2w+1.
// Lane lp (0..31) owns samples 3lp, 3lp+1, 3lp+2 and midpoints 3lp..3lp+2
// (midpoint 95 at lp=31 masked). Log-space transmittance:
//   dd_i = (d_{i+1}-d_i)*log2(1+exp((s_i+s_{i+1})/2));  T_j = exp2(-prefix)
//   w_i = T_i - T_{i+1};  rgb/dep via v_j = 0.5*(T_{j-1}-T_{j+1});
//   1-wtot = T_95 (telescoping).
// Local 3-term cumsum + 5-DPP 32-lane scan; 4x 5-DPP 32-lane reductions.
// Slot mode: block depth bounds -> ws[blk], ws[nblocks+blk]; tail clamps.
// ---------------------------------------------------------------------------
template <bool SLOT>
__global__ __launch_bounds__(WPB * 64) void march_kernel(
    const float* __restrict__ colors,
    const float* __restrict__ dens,
    const float* __restrict__ depths,
    const int* __restrict__ white_back,
    unsigned int* __restrict__ ws,
    float* __restrict__ out_rgb,   // [nrays,3]
    float* __restrict__ out_dep,   // [nrays] raw
    float* __restrict__ out_w,     // [nrays,95]
    int nrays, int nblocks) {
    __shared__ float smn[WPB], smx[WPB];
    const int wv = threadIdx.x >> 6;
    const int l = threadIdx.x & 63;
    const int lp = l & 31;
    const int ray0 = (blockIdx.x * WPB + wv) * 2 + (l >> 5);
    const bool valid = (ray0 < nrays);
    const int ray = valid ? ray0 : (nrays - 1);
    const int wb = *white_back;

    const int doff = ray * S + 3 * lp;          // 32-bit offsets throughout
    const int coff = ray * (3 * S) + 9 * lp;

    const float3 dv = *(const float3*)(depths + doff);
    const float3 sv = *(const float3*)(dens + doff);
    const float3 ca = *(const float3*)(colors + coff);      // color sample 3lp
    const float3 cb = *(const float3*)(colors + coff + 3);  // 3lp+1
    const float3 cc = *(const float3*)(colors + coff + 6);  // 3lp+2

    // ---- wave depth bounds (sorted): d[0] at lanes 0/32, d[95]=dv.z at 31/63
    float rmn = fminf(rdlane(dv.x, 0), rdlane(dv.x, 32));
    float rmx = fmaxf(rdlane(dv.z, 31), rdlane(dv.z, 63));
    if (l == 0) { smn[wv] = rmn; smx[wv] = rmx; }
    __syncthreads();
    if (threadIdx.x == 0) {
        float bmn = smn[0], bmx = smx[0];
#pragma unroll
        for (int i = 1; i < WPB; ++i) {
            bmn = fminf(bmn, smn[i]);
            bmx = fmaxf(bmx, smx[i]);
        }
        if (SLOT) {
            float* sl = (float*)ws;
            sl[blockIdx.x] = bmn;
            sl[nblocks + blockIdx.x] = bmx;
        } else {
            atomicMin((int*)&ws[0], __float_as_int(bmn));
            atomicMax((int*)&ws[1], __float_as_int(bmx));
        }
    }

    // ---- neighbor sample 3lp+3 (lane+1's first); 32-boundary leak lands
    // only in masked midpoint 95 -> no patch needed
    float dn = wshl1(dv.x);
    float sn = wshl1(sv.x);

    // ---- softplus (log2 space) per owned midpoint
    const float C1 = 0.5f * L2E;
    float x0 = (sv.x + sv.y) * C1;
    float x1 = (sv.y + sv.z) * C1;
    float x2 = (sv.z + sn) * C1;
    float sp0 = fmaxf(x0, 0.f) + flog2(1.f + fexp2(-fabsf(x0)));
    float sp1 = fmaxf(x1, 0.f) + flog2(1.f + fexp2(-fabsf(x1)));
    float sp2 = fmaxf(x2, 0.f) + flog2(1.f + fexp2(-fabsf(x2)));
    float dd0 = (dv.y - dv.x) * sp0;
    float dd1 = (dv.z - dv.y) * sp1;
    float dd2 = (lp < 31) ? (dn - dv.z) * sp2 : 0.f;   // midpoint 95 masked

    // ---- local cumsum + 32-lane scan
    float cum1 = dd0 + dd1;
    float cum2 = cum1 + dd2;
    float incl = scan32(cum2);
    float base = incl - cum2;        // exclusive prefix (sum of prior lanes)

    float T0 = fexp2(-base);         // T at sample 3lp
    float T1 = fexp2(-(base + dd0)); // 3lp+1
    float T2 = fexp2(-(base + cum1)); // 3lp+2
    float T3 = fexp2(-incl);         // 3lp+3 (lp=31: T_96 := T_95)

    float w0 = T0 - T1;              // weight midpoint 3lp
    float w1 = T1 - T2;              // 3lp+1
    float w2 = T2 - T3;              // 3lp+2 (invalid at lp=31)

    // ---- per-sample coefficients v_j (0.5 deferred to output)
    float Tm1 = wshr1(T2);           // prev lane's T(3lp-1)
    if (lp == 0) Tm1 = 1.f;          // T_{-1} := T_0 = 1
    float v0 = Tm1 - T1;
    float v1 = T0 - T2;
    float v2 = T1 - T3;

    // ---- weighted accumulation + 32-lane reductions (totals at lanes 31/63)
    float racc = v0 * ca.x + v1 * cb.x + v2 * cc.x;
    float gacc = v0 * ca.y + v1 * cb.y + v2 * cc.y;
    float bacc = v0 * ca.z + v1 * cb.z + v2 * cc.z;
    float dacc = v0 * dv.x + v1 * dv.y + v2 * dv.z;
    racc = scan32(racc);
    gacc = scan32(gacc);
    bacc = scan32(bacc);
    dacc = scan32(dacc);

    if (!valid) return;   // after syncthreads; only stores below

    const int woff = ray * SM + 3 * lp;
    out_w[woff] = w0;
    out_w[woff + 1] = w1;            // 3lp+1 <= 94 always
    if (lp < 31) out_w[woff + 2] = w2;

    if (lp == 31) {                  // lane 31 -> ray A, lane 63 -> ray B
        float T95 = T2;              // T at sample 95 (local at lp=31)
        float rr = 0.5f * racc, gg = 0.5f * gacc, bb = 0.5f * bacc;
        if (wb) { rr += T95; gg += T95; bb += T95; }  // 1-wtot = T_95
        out_rgb[ray * 3 + 0] = rr;
        out_rgb[ray * 3 + 1] = gg;
        out_rgb[ray * 3 + 2] = bb;
        float cd = 0.5f * dacc;
        if (isnan(cd)) cd = INFINITY;  // nan_to_num(nan=inf)
        out_dep[ray] = cd;             // clamped by tail_kernel
    }
}

// Merged finalize+clamp: every block redundantly reduces the slot arrays
// (float4, L2-resident, 2 iters/thread at nblocks=2048) then clamps its
// contiguous chunk of out_dep.
__global__ __launch_bounds__(256) void tail_kernel(
    float* __restrict__ dep, const unsigned int* __restrict__ ws,
    int n, int nblocks, int slotMode) {
    float gmn, gmx;
    if (slotMode) {
        const float* sl = (const float*)ws;
        float mn = INFINITY, mx = -INFINITY;
        const int nv = nblocks >> 2;                    // float4 count
        const float4* mn4 = (const float4*)sl;
        const float4* mx4 = (const float4*)(sl + nblocks);
        for (int i = threadIdx.x; i < nv; i += 256) {
            float4 a = mn4[i];
            float4 b = mx4[i];
            mn = fminf(mn, fminf(fminf(a.x, a.y), fminf(a.z, a.w)));
            mx = fmaxf(mx, fmaxf(fmaxf(b.x, b.y), fmaxf(b.z, b.w)));
        }
        for (int i = (nv << 2) + threadIdx.x; i < nblocks; i += 256) {
            mn = fminf(mn, sl[i]);
            mx = fmaxf(mx, sl[nblocks + i]);
        }
#pragma unroll
        for (int off = 32; off >= 1; off >>= 1) {
            mn = fminf(mn, __shfl_xor(mn, off));
            mx = fmaxf(mx, __shfl_xor(mx, off));
        }
        __shared__ float a[4], b[4];
        const int wv = threadIdx.x >> 6;
        if ((threadIdx.x & 63) == 0) { a[wv] = mn; b[wv] = mx; }
        __syncthreads();
        gmn = fminf(fminf(a[0], a[1]), fminf(a[2], a[3]));
        gmx = fmaxf(fmaxf(b[0], b[1]), fmaxf(b[2], b[3]));
    } else {
        gmn = __int_as_float((int)ws[0]);
        gmx = __int_as_float((int)ws[1]);
    }
    int i = blockIdx.x * 256 + threadIdx.x;
    if (i < n) dep[i] = fminf(fmaxf(dep[i], gmn), gmx);
}

extern "C" void kernel_launch(void* const* d_in, const int* in_sizes, int n_in,
                              void* d_out, int out_size, void* d_ws, size_t ws_size,
                              hipStream_t stream) {
    const float* colors = (const float*)d_in[0];
    const float* dens = (const float*)d_in[1];
    const float* depths = (const float*)d_in[2];
    const int* white_back = (const int*)d_in[3];

    const int nrays = in_sizes[1] / S;  // densities: nrays * S
    unsigned int* ws = (unsigned int*)d_ws;

    float* out_rgb = (float*)d_out;                // nrays*3
    float* out_dep = out_rgb + (size_t)nrays * 3;  // nrays
    float* out_w = out_dep + nrays;                // nrays*95

    const int raysPB = 2 * WPB;                    // 32 rays per block
    const int nblocks = (nrays + raysPB - 1) / raysPB;
    const bool slot = ws_size >= (size_t)(2 * nblocks) * sizeof(float);

    if (slot) {
        march_kernel<true><<<nblocks, WPB * 64, 0, stream>>>(
            colors, dens, depths, white_back, ws, out_rgb, out_dep, out_w,
            nrays, nblocks);
    } else {
        init_ws_kernel<<<1, 1, 0, stream>>>(ws);
        march_kernel<false><<<nblocks, WPB * 64, 0, stream>>>(
            colors, dens, depths, white_back, ws, out_rgb, out_dep, out_w,
            nrays, nblocks);
    }
    tail_kernel<<<(nrays + 255) / 256, 256, 0, stream>>>(
        out_dep, ws, nrays, nblocks, slot ? 1 : 0);
}

// Round 12
// 29.116 us; speedup vs baseline: 1.6745x; 1.1086x over previous
//
#include <hip/hip_runtime.h>
#include <math.h>

#define S 96
#define SM 95
#define WPB 16           // waves per march block; 2 rays/wave -> 32 rays/block
#define L2E 1.4426950408889634f

__device__ __forceinline__ float fexp2(float x) {
#if __has_builtin(__builtin_amdgcn_exp2f)
    return __builtin_amdgcn_exp2f(x);   // v_exp_f32: 2^x
#else
    return exp2f(x);
#endif
}
__device__ __forceinline__ float flog2(float x) {
#if __has_builtin(__builtin_amdgcn_logf)
    return __builtin_amdgcn_logf(x);    // v_log_f32: log2(x)
#else
    return log2f(x);
#endif
}

// DPP helper: invalid/masked lanes receive `old`.
template <int CTRL, int RMASK>
__device__ __forceinline__ float updpp(float old, float src) {
    return __int_as_float(__builtin_amdgcn_update_dpp(
        __float_as_int(old), __float_as_int(src), CTRL, RMASK, 0xF, false));
}
template <int CTRL, int RMASK>
__device__ __forceinline__ float updpp0(float src) {
    return __int_as_float(__builtin_amdgcn_update_dpp(
        0, __float_as_int(src), CTRL, RMASK, 0xF, false));
}

// 32-lane inclusive prefix-sum within each wave half (5 DPP, all VALU).
// After: lane 31 holds sum of lanes 0..31, lane 63 holds sum of 32..63.
__device__ __forceinline__ float scan32(float x) {
    x += updpp0<0x111, 0xF>(x);  // row_shr:1
    x += updpp0<0x112, 0xF>(x);  // row_shr:2
    x += updpp0<0x114, 0xF>(x);  // row_shr:4
    x += updpp0<0x118, 0xF>(x);  // row_shr:8
    x += updpp0<0x142, 0xA>(x);  // row_bcast:15 -> rows 1,3 (stays in half)
    return x;
}
// 32-lane min/max ladders (identity-preserving via `old`)
__device__ __forceinline__ float redmin32(float x) {
    x = fminf(x, updpp<0x111, 0xF>(INFINITY, x));
    x = fminf(x, updpp<0x112, 0xF>(INFINITY, x));
    x = fminf(x, updpp<0x114, 0xF>(INFINITY, x));
    x = fminf(x, updpp<0x118, 0xF>(INFINITY, x));
    x = fminf(x, updpp<0x142, 0xA>(INFINITY, x));
    return x;                    // lane 31 = min of lanes 0..31
}
__device__ __forceinline__ float redmax32(float x) {
    x = fmaxf(x, updpp<0x111, 0xF>(-INFINITY, x));
    x = fmaxf(x, updpp<0x112, 0xF>(-INFINITY, x));
    x = fmaxf(x, updpp<0x114, 0xF>(-INFINITY, x));
    x = fmaxf(x, updpp<0x118, 0xF>(-INFINITY, x));
    x = fmaxf(x, updpp<0x143, 0xC>(-INFINITY, x));  // row_bcast:31 -> row 2,3
    return x;                    // lane 63 = max of lanes 32..63
}

__device__ __forceinline__ float rdlane(float x, int lane) {
    return __int_as_float(__builtin_amdgcn_readlane(__float_as_int(x), lane));
}
// wave-wide lane shifts (VALU): shr1: lane l <- l-1; shl1: lane l <- l+1
__device__ __forceinline__ float wshr1(float x) { return updpp0<0x138, 0xF>(x); }
__device__ __forceinline__ float wshl1(float x) { return updpp0<0x130, 0xF>(x); }

// atomic-fallback init (only if ws too small for slots)
__global__ void init_ws_kernel(unsigned int* ws) {
    ws[0] = 0x7F800000u;  // +inf
    ws[1] = 0xFF800000u;  // -inf
}

// ---------------------------------------------------------------------------
// TWO rays per wave: lanes 0-31 = ray 2w, lanes 32-63 = ray 2w+1.
// Lane lp (0..31) owns samples 3lp..3lp+2 and midpoints 3lp..3lp+2
// (midpoint 95 at lp=31 masked). Log-space transmittance:
//   dd_i = (d_{i+1}-d_i)*log2(1+exp((s_i+s_{i+1})/2));  T_j = exp2(-prefix)
//   w_i = T_i - T_{i+1};  rgb/dep via v_j = 0.5*(T_{j-1}-T_{j+1});
//   1-wtot = T_95 (telescoping).
// No LDS, no __syncthreads: wave 0 alone gathers the block's 32 ray depth
// bounds (d[r][0] lanes 0-31, d[r][95] lanes 32-63) and writes the slot.
// Depth stored raw (NaN->inf); tail_kernel clamps with global min/max.
// ---------------------------------------------------------------------------
template <bool SLOT>
__global__ __launch_bounds__(WPB * 64) void march_kernel(
    const float* __restrict__ colors,
    const float* __restrict__ dens,
    const float* __restrict__ depths,
    const int* __restrict__ white_back,
    unsigned int* __restrict__ ws,
    float* __restrict__ out_rgb,   // [nrays,3]
    float* __restrict__ out_dep,   // [nrays] raw
    float* __restrict__ out_w,     // [nrays,95]
    int nrays, int nblocks) {
    const int wv = threadIdx.x >> 6;
    const int l = threadIdx.x & 63;
    const int lp = l & 31;
    const int ray0 = (blockIdx.x * WPB + wv) * 2 + (l >> 5);
    const bool valid = (ray0 < nrays);
    const int ray = valid ? ray0 : (nrays - 1);
    const int wb = *white_back;

    // ---- wave 0 only: block depth bounds (no barrier, no LDS)
    if (wv == 0) {
        int r = blockIdx.x * (2 * WPB) + lp;
        if (r >= nrays) r = nrays - 1;
        float v = depths[r * S + ((l < 32) ? 0 : SM)];
        float mn = redmin32((l < 32) ? v : INFINITY);     // lane 31
        float mx = redmax32((l < 32) ? INFINITY : v);     // lane 63
        float bmn = rdlane(mn, 31);
        float bmx = rdlane(mx, 63);
        if (l == 0) {
            if (SLOT) {
                float* sl = (float*)ws;
                sl[blockIdx.x] = bmn;
                sl[nblocks + blockIdx.x] = bmx;
            } else {
                atomicMin((int*)&ws[0], __float_as_int(bmn));
                atomicMax((int*)&ws[1], __float_as_int(bmx));
            }
        }
    }

    const int doff = ray * S + 3 * lp;          // 32-bit offsets throughout
    const int coff = ray * (3 * S) + 9 * lp;

    const float3 dv = *(const float3*)(depths + doff);
    const float3 sv = *(const float3*)(dens + doff);
    const float3 ca = *(const float3*)(colors + coff);      // color sample 3lp
    const float3 cb = *(const float3*)(colors + coff + 3);  // 3lp+1
    const float3 cc = *(const float3*)(colors + coff + 6);  // 3lp+2

    // ---- neighbor sample 3lp+3 (lane+1's first); 32-boundary leak lands
    // only in masked midpoint 95 -> no patch needed
    float dn = wshl1(dv.x);
    float sn = wshl1(sv.x);

    // ---- softplus (log2 space) per owned midpoint
    const float C1 = 0.5f * L2E;
    float x0 = (sv.x + sv.y) * C1;
    float x1 = (sv.y + sv.z) * C1;
    float x2 = (sv.z + sn) * C1;
    float sp0 = fmaxf(x0, 0.f) + flog2(1.f + fexp2(-fabsf(x0)));
    float sp1 = fmaxf(x1, 0.f) + flog2(1.f + fexp2(-fabsf(x1)));
    float sp2 = fmaxf(x2, 0.f) + flog2(1.f + fexp2(-fabsf(x2)));
    float dd0 = (dv.y - dv.x) * sp0;
    float dd1 = (dv.z - dv.y) * sp1;
    float dd2 = (lp < 31) ? (dn - dv.z) * sp2 : 0.f;   // midpoint 95 masked

    // ---- local cumsum + 32-lane scan
    float cum1 = dd0 + dd1;
    float cum2 = cum1 + dd2;
    float incl = scan32(cum2);
    float base = incl - cum2;        // exclusive prefix (sum of prior lanes)

    float T0 = fexp2(-base);          // T at sample 3lp
    float T1 = fexp2(-(base + dd0));  // 3lp+1
    float T2 = fexp2(-(base + cum1)); // 3lp+2
    float T3 = fexp2(-incl);          // 3lp+3 (lp=31: T_96 := T_95)

    float w0 = T0 - T1;              // weight midpoint 3lp
    float w1 = T1 - T2;              // 3lp+1
    float w2 = T2 - T3;              // 3lp+2 (invalid at lp=31)

    // ---- per-sample coefficients v_j (0.5 deferred to output)
    float Tm1 = wshr1(T2);           // prev lane's T(3lp-1)
    if (lp == 0) Tm1 = 1.f;          // T_{-1} := T_0 = 1
    float v0 = Tm1 - T1;
    float v1 = T0 - T2;
    float v2 = T1 - T3;

    // ---- weighted accumulation + 32-lane reductions (totals at lanes 31/63)
    float racc = v0 * ca.x + v1 * cb.x + v2 * cc.x;
    float gacc = v0 * ca.y + v1 * cb.y + v2 * cc.y;
    float bacc = v0 * ca.z + v1 * cb.z + v2 * cc.z;
    float dacc = v0 * dv.x + v1 * dv.y + v2 * dv.z;
    racc = scan32(racc);
    gacc = scan32(gacc);
    bacc = scan32(bacc);
    dacc = scan32(dacc);

    if (!valid) return;   // no barriers below; only stores

    const int woff = ray * SM + 3 * lp;
    if (lp < 31) {
        float3 wv3 = {w0, w1, w2};
        *(float3*)(out_w + woff) = wv3;          // dwordx3 store
    } else {
        out_w[woff] = w0;                         // midpoints 93, 94
        out_w[woff + 1] = w1;
    }

    if (lp == 31) {                  // lane 31 -> ray A, lane 63 -> ray B
        float T95 = T2;              // T at sample 95 (local at lp=31)
        float rr = 0.5f * racc, gg = 0.5f * gacc, bb = 0.5f * bacc;
        if (wb) { rr += T95; gg += T95; bb += T95; }  // 1-wtot = T_95
        out_rgb[ray * 3 + 0] = rr;
        out_rgb[ray * 3 + 1] = gg;
        out_rgb[ray * 3 + 2] = bb;
        float cd = 0.5f * dacc;
        if (isnan(cd)) cd = INFINITY;  // nan_to_num(nan=inf)
        out_dep[ray] = cd;             // clamped by tail_kernel
    }
}

// Merged finalize+clamp: every block redundantly reduces the slot arrays
// (float4, L2-resident, 2 iters/thread at nblocks=2048) then clamps its
// contiguous chunk of out_dep.
__global__ __launch_bounds__(256) void tail_kernel(
    float* __restrict__ dep, const unsigned int* __restrict__ ws,
    int n, int nblocks, int slotMode) {
    float gmn, gmx;
    if (slotMode) {
        const float* sl = (const float*)ws;
        float mn = INFINITY, mx = -INFINITY;
        const int nv = nblocks >> 2;                    // float4 count
        const float4* mn4 = (const float4*)sl;
        const float4* mx4 = (const float4*)(sl + nblocks);
        for (int i = threadIdx.x; i < nv; i += 256) {
            float4 a = mn4[i];
            float4 b = mx4[i];
            mn = fminf(mn, fminf(fminf(a.x, a.y), fminf(a.z, a.w)));
            mx = fmaxf(mx, fmaxf(fmaxf(b.x, b.y), fmaxf(b.z, b.w)));
        }
        for (int i = (nv << 2) + threadIdx.x; i < nblocks; i += 256) {
            mn = fminf(mn, sl[i]);
            mx = fmaxf(mx, sl[nblocks + i]);
        }
#pragma unroll
        for (int off = 32; off >= 1; off >>= 1) {
            mn = fminf(mn, __shfl_xor(mn, off));
            mx = fmaxf(mx, __shfl_xor(mx, off));
        }
        __shared__ float a[4], b[4];
        const int wv = threadIdx.x >> 6;
        if ((threadIdx.x & 63) == 0) { a[wv] = mn; b[wv] = mx; }
        __syncthreads();
        gmn = fminf(fminf(a[0], a[1]), fminf(a[2], a[3]));
        gmx = fmaxf(fmaxf(b[0], b[1]), fmaxf(b[2], b[3]));
    } else {
        gmn = __int_as_float((int)ws[0]);
        gmx = __int_as_float((int)ws[1]);
    }
    int i = blockIdx.x * 256 + threadIdx.x;
    if (i < n) dep[i] = fminf(fmaxf(dep[i], gmn), gmx);
}

extern "C" void kernel_launch(void* const* d_in, const int* in_sizes, int n_in,
                              void* d_out, int out_size, void* d_ws, size_t ws_size,
                              hipStream_t stream) {
    const float* colors = (const float*)d_in[0];
    const float* dens = (const float*)d_in[1];
    const float* depths = (const float*)d_in[2];
    const int* white_back = (const int*)d_in[3];

    const int nrays = in_sizes[1] / S;  // densities: nrays * S
    unsigned int* ws = (unsigned int*)d_ws;

    float* out_rgb = (float*)d_out;                // nrays*3
    float* out_dep = out_rgb + (size_t)nrays * 3;  // nrays
    float* out_w = out_dep + nrays;                // nrays*95

    const int raysPB = 2 * WPB;                    // 32 rays per block
    const int nblocks = (nrays + raysPB - 1) / raysPB;
    const bool slot = ws_size >= (size_t)(2 * nblocks) * sizeof(float);

    if (slot) {
        march_kernel<true><<<nblocks, WPB * 64, 0, stream>>>(
            colors, dens, depths, white_back, ws, out_rgb, out_dep, out_w,
            nrays, nblocks);
    } else {
        init_ws_kernel<<<1, 1, 0, stream>>>(ws);
        march_kernel<false><<<nblocks, WPB * 64, 0, stream>>>(
            colors, dens, depths, white_back, ws, out_rgb, out_dep, out_w,
            nrays, nblocks);
    }
    tail_kernel<<<(nrays + 255) / 256, 256, 0, stream>>>(
        out_dep, ws, nrays, nblocks, slot ? 1 : 0);
}